// Round 1
// baseline (636.909 us; speedup 1.0000x reference)
//
#include <hip/hip_runtime.h>
#include <hip/hip_bf16.h>
#include <stdint.h>

#define N_NODES 100000
#define N_EDGES 1600000
#define DIM 128
#define N_GRAPHS 128
#define LDA 136   // padded LDS stride in bf16 elems: 272B rows -> bank step 4, 2-way max (free)

typedef unsigned int uint32;
typedef unsigned short ushort16;

typedef __bf16 bf16x8 __attribute__((ext_vector_type(8)));
typedef float fx4 __attribute__((ext_vector_type(4)));

__device__ __forceinline__ float bfLo(uint32 u){ return __builtin_bit_cast(float, (uint32)(u << 16)); }
__device__ __forceinline__ float bfHi(uint32 u){ return __builtin_bit_cast(float, (uint32)(u & 0xFFFF0000u)); }
__device__ __forceinline__ ushort16 f2bf(float f){
  uint32 u = __builtin_bit_cast(uint32, f);
  u = u + 0x7FFFu + ((u >> 16) & 1u);   // round-to-nearest-even
  return (ushort16)(u >> 16);
}
__device__ __forceinline__ uint32 pack2(float a, float b){
  return (uint32)f2bf(a) | ((uint32)f2bf(b) << 16);
}
__device__ __forceinline__ uint32 addpack(uint32 x, uint32 a){
  return pack2(bfLo(x)+bfLo(a), bfHi(x)+bfHi(a));
}

// ---------- conversion kernels (once per launch) ----------
__global__ __launch_bounds__(256) void k_cvt_x(const float* __restrict__ x, ushort16* __restrict__ P){
  int idx = (blockIdx.x*256 + threadIdx.x) * 8;   // 6250 blocks * 256 * 8 = 12.8M exactly
  float4 v0 = *(const float4*)(x + idx);
  float4 v1 = *(const float4*)(x + idx + 4);
  uint4 o;
  o.x = pack2(v0.x, v0.y); o.y = pack2(v0.z, v0.w);
  o.z = pack2(v1.x, v1.y); o.w = pack2(v1.z, v1.w);
  *(uint4*)(P + idx) = o;
}

// build Wt[layer][n][k] = W[layer][k][n] in bf16 (so MFMA B-frags are contiguous in k)
__global__ __launch_bounds__(256) void k_cvt_w(const float* __restrict__ W1, const float* __restrict__ W2,
                                               ushort16* __restrict__ WtA, ushort16* __restrict__ WtB){
  int idx = blockIdx.x*256 + threadIdx.x;          // 0..98303
  const float* src = (idx < 49152) ? W1 : W2;
  ushort16*    dst = (idx < 49152) ? WtA : WtB;
  int il = idx % 49152;
  int layer = il >> 14;
  int n = (il >> 7) & 127;
  int k = il & 127;
  dst[layer*16384 + n*128 + k] = f2bf(src[layer*16384 + k*128 + n]);
}

// ---------- CSR build ----------
__global__ __launch_bounds__(256) void k_count(const int* __restrict__ ei, int* __restrict__ deg){
  int e = blockIdx.x*256 + threadIdx.x;
  if (e < N_EDGES) atomicAdd(&deg[ei[N_EDGES + e]], 1);
}

__global__ __launch_bounds__(256) void k_scan1(const int* __restrict__ deg, int* __restrict__ partial){
  __shared__ int s[256];
  int b = blockIdx.x, t = threadIdx.x;
  int base = b*1024 + t*4;
  int v = 0;
  #pragma unroll
  for (int i=0;i<4;++i){ int n = base+i; if (n < N_NODES) v += deg[n]; }
  s[t] = v; __syncthreads();
  for (int off=128; off>0; off>>=1){ if (t<off) s[t]+=s[t+off]; __syncthreads(); }
  if (t==0) partial[b] = s[0];
}

__global__ void k_scan2(const int* __restrict__ partial, int* __restrict__ poffset, int* __restrict__ rowptr){
  __shared__ int s[128];
  int t = threadIdx.x;
  int v = (t < 98) ? partial[t] : 0;
  s[t] = v; __syncthreads();
  for (int off=1; off<128; off<<=1){
    int x = (t>=off) ? s[t-off] : 0; __syncthreads(); s[t]+=x; __syncthreads();
  }
  if (t < 98) poffset[t] = s[t] - v;     // exclusive
  if (t == 127) rowptr[N_NODES] = s[127];
}

__global__ __launch_bounds__(256) void k_scan3(const int* __restrict__ deg, const int* __restrict__ poffset,
                                               int* __restrict__ rowptr, int* __restrict__ cursor){
  __shared__ int s[256];
  int b = blockIdx.x, t = threadIdx.x;
  int base = b*1024 + t*4;
  int v0=0,v1=0,v2=0,v3=0;
  if (base+0 < N_NODES) v0 = deg[base+0];
  if (base+1 < N_NODES) v1 = deg[base+1];
  if (base+2 < N_NODES) v2 = deg[base+2];
  if (base+3 < N_NODES) v3 = deg[base+3];
  int tsum = v0+v1+v2+v3;
  s[t] = tsum; __syncthreads();
  for (int off=1; off<256; off<<=1){
    int x = (t>=off) ? s[t-off] : 0; __syncthreads(); s[t]+=x; __syncthreads();
  }
  int excl = s[t] - tsum + poffset[b];
  if (base+0 < N_NODES){ rowptr[base+0]=excl; cursor[base+0]=excl; excl+=v0; }
  if (base+1 < N_NODES){ rowptr[base+1]=excl; cursor[base+1]=excl; excl+=v1; }
  if (base+2 < N_NODES){ rowptr[base+2]=excl; cursor[base+2]=excl; excl+=v2; }
  if (base+3 < N_NODES){ rowptr[base+3]=excl; cursor[base+3]=excl; excl+=v3; }
}

__global__ __launch_bounds__(256) void k_fill(const int* __restrict__ ei, int* __restrict__ cursor,
                                              int* __restrict__ colx){
  int e = blockIdx.x*256 + threadIdx.x;
  if (e < N_EDGES){
    int d = ei[N_EDGES + e];
    int pos = atomicAdd(&cursor[d], 1);
    colx[pos] = ei[e];   // src
  }
}

// ---------- aggregation: one wave per node, CSR gather, no f32 atomics ----------
__global__ __launch_bounds__(256) void k_agg(const ushort16* __restrict__ xb, ushort16* __restrict__ ob,
                                             const int* __restrict__ rowptr, const int* __restrict__ colx){
  int node = (blockIdx.x*256 + threadIdx.x) >> 6;   // 25000 blocks * 4 waves = 100000
  int lane = threadIdx.x & 63;
  int start = rowptr[node], end = rowptr[node+1];
  float a0 = 0.f, a1 = 0.f;
  int j = start;
  for (; j + 4 <= end; j += 4){
    int s0 = colx[j], s1 = colx[j+1], s2 = colx[j+2], s3 = colx[j+3];
    uint32 u0 = *(const uint32*)(xb + s0*128 + lane*2);
    uint32 u1 = *(const uint32*)(xb + s1*128 + lane*2);
    uint32 u2 = *(const uint32*)(xb + s2*128 + lane*2);
    uint32 u3 = *(const uint32*)(xb + s3*128 + lane*2);
    a0 += (bfLo(u0) + bfLo(u1)) + (bfLo(u2) + bfLo(u3));
    a1 += (bfHi(u0) + bfHi(u1)) + (bfHi(u2) + bfHi(u3));
  }
  for (; j < end; ++j){
    int sx = colx[j];
    uint32 u = *(const uint32*)(xb + sx*128 + lane*2);
    a0 += bfLo(u); a1 += bfHi(u);
  }
  *(uint32*)(ob + node*128 + lane*2) = pack2(a0, a1);
}

// ---------- fused GIN MLP: out = relu((x+agg)@W1 + b1)@W2 + b2, in-place over agg buffer ----------
__global__ __launch_bounds__(256) void k_mlp(const ushort16* __restrict__ xb, ushort16* __restrict__ hb,
                                             const ushort16* __restrict__ Wt1, const float* __restrict__ b1,
                                             const ushort16* __restrict__ Wt2, const float* __restrict__ b2){
  __shared__ __attribute__((aligned(16))) ushort16 sA[64 * LDA];   // h0 tile, later reused as h tile
  __shared__ __attribute__((aligned(16))) ushort16 sW[128 * LDA];  // W^T (bf16), W1 then W2
  int t = threadIdx.x;
  int row0 = blockIdx.x * 64;

  int sr = t >> 4;            // 0..15
  int sc = (t & 15) * 8;      // 0,8,...,120

  // stage sA = x + agg (bf16), zeros for OOB rows
  #pragma unroll
  for (int it = 0; it < 4; ++it){
    int row = it*16 + sr;
    int g = row0 + row;
    uint4 o;
    if (g < N_NODES){
      uint4 xv = *(const uint4*)(xb + g*128 + sc);
      uint4 av = *(const uint4*)(hb + g*128 + sc);
      o.x = addpack(xv.x, av.x); o.y = addpack(xv.y, av.y);
      o.z = addpack(xv.z, av.z); o.w = addpack(xv.w, av.w);
    } else { o.x = o.y = o.z = o.w = 0u; }
    *(uint4*)(sA + row*LDA + sc) = o;
  }
  // stage sW = W1^T
  #pragma unroll
  for (int it = 0; it < 8; ++it){
    int row = it*16 + sr;
    *(uint4*)(sW + row*LDA + sc) = *(const uint4*)(Wt1 + row*128 + sc);
  }
  __syncthreads();

  int wave = t >> 6, l = t & 63, m = l & 15, kg = l >> 4;
  fx4 acc[8];
  #pragma unroll
  for (int nt = 0; nt < 8; ++nt) acc[nt] = (fx4){0.f,0.f,0.f,0.f};

  const ushort16* aBase = sA + (wave*16 + m)*LDA + kg*8;
  const ushort16* bBase = sW + m*LDA + kg*8;

  // GEMM1
  #pragma unroll
  for (int kt = 0; kt < 4; ++kt){
    bf16x8 av = *(const bf16x8*)(aBase + kt*32);
    #pragma unroll
    for (int nt = 0; nt < 8; ++nt){
      bf16x8 bv = *(const bf16x8*)(bBase + nt*16*LDA + kt*32);
      acc[nt] = __builtin_amdgcn_mfma_f32_16x16x32_bf16(av, bv, acc[nt], 0, 0, 0);
    }
  }
  __syncthreads();   // all reads of sA/sW done

  // h = relu(acc + b1) -> sA (C-layout: col = m + 16*nt, row = kg*4 + r)
  #pragma unroll
  for (int nt = 0; nt < 8; ++nt){
    float bv = b1[nt*16 + m];
    #pragma unroll
    for (int r = 0; r < 4; ++r){
      float v = acc[nt][r] + bv;
      v = fmaxf(v, 0.f);
      sA[(wave*16 + kg*4 + r)*LDA + nt*16 + m] = f2bf(v);
    }
  }
  // stage sW = W2^T
  #pragma unroll
  for (int it = 0; it < 8; ++it){
    int row = it*16 + sr;
    *(uint4*)(sW + row*LDA + sc) = *(const uint4*)(Wt2 + row*128 + sc);
  }
  __syncthreads();

  #pragma unroll
  for (int nt = 0; nt < 8; ++nt) acc[nt] = (fx4){0.f,0.f,0.f,0.f};

  // GEMM2
  #pragma unroll
  for (int kt = 0; kt < 4; ++kt){
    bf16x8 av = *(const bf16x8*)(aBase + kt*32);
    #pragma unroll
    for (int nt = 0; nt < 8; ++nt){
      bf16x8 bv = *(const bf16x8*)(bBase + nt*16*LDA + kt*32);
      acc[nt] = __builtin_amdgcn_mfma_f32_16x16x32_bf16(av, bv, acc[nt], 0, 0, 0);
    }
  }

  // epilogue: out = acc + b2 -> hb (bf16), same rows this block consumed (in-place safe)
  #pragma unroll
  for (int nt = 0; nt < 8; ++nt){
    float bv = b2[nt*16 + m];
    #pragma unroll
    for (int r = 0; r < 4; ++r){
      int g = row0 + wave*16 + kg*4 + r;
      if (g < N_NODES){
        float v = acc[nt][r] + bv;
        hb[g*128 + nt*16 + m] = f2bf(v);
      }
    }
  }
}

// ---------- sum-pool per graph (batch sorted) ----------
__device__ __forceinline__ int lower_bound_i(const int* __restrict__ a, int n, int key){
  int lo = 0, hi = n;
  while (lo < hi){ int mid = (lo + hi) >> 1; if (a[mid] < key) lo = mid + 1; else hi = mid; }
  return lo;
}

__global__ __launch_bounds__(256) void k_pool(const ushort16* __restrict__ xb, const int* __restrict__ batch,
                                              float* __restrict__ out){
  int g = blockIdx.x >> 2;
  int p = blockIdx.x & 3;
  int start = lower_bound_i(batch, N_NODES, g);
  int end   = lower_bound_i(batch, N_NODES, g + 1);
  int t = threadIdx.x;
  int c = t & 127;
  int h = t >> 7;
  float acc = 0.f;
  for (int r = start + p*2 + h; r < end; r += 8){
    uint32 u = (uint32)xb[r*128 + c];
    acc += __builtin_bit_cast(float, (uint32)(u << 16));
  }
  __shared__ float red[256];
  red[t] = acc; __syncthreads();
  if (t < 128) atomicAdd(&out[g*128 + c], red[t] + red[t + 128]);
}

// ---------- launch ----------
extern "C" void kernel_launch(void* const* d_in, const int* in_sizes, int n_in,
                              void* d_out, int out_size, void* d_ws, size_t ws_size,
                              hipStream_t stream) {
  const float* x   = (const float*)d_in[0];
  const float* W1  = (const float*)d_in[1];
  const float* b1  = (const float*)d_in[2];
  const float* W2  = (const float*)d_in[3];
  const float* b2  = (const float*)d_in[4];
  const int*   ei  = (const int*)d_in[5];
  const int*   bat = (const int*)d_in[6];
  float* out = (float*)d_out;

  char* w = (char*)d_ws;
  auto carve = [&](size_t bytes) -> char* {
    char* p = w; w += (bytes + 255) & ~(size_t)255; return p;
  };
  ushort16* P    = (ushort16*)carve((size_t)N_NODES * DIM * 2);
  ushort16* Q    = (ushort16*)carve((size_t)N_NODES * DIM * 2);
  ushort16* WtA  = (ushort16*)carve(3 * 16384 * 2);
  ushort16* WtB  = (ushort16*)carve(3 * 16384 * 2);
  int* deg       = (int*)carve((size_t)N_NODES * 4);
  int* rowptr    = (int*)carve((size_t)(N_NODES + 1) * 4);
  int* cursor    = (int*)carve((size_t)N_NODES * 4);
  int* colx      = (int*)carve((size_t)N_EDGES * 4);
  int* partial   = (int*)carve(98 * 4);
  int* poffset   = (int*)carve(98 * 4);

  hipMemsetAsync(deg, 0, (size_t)N_NODES * 4, stream);
  hipMemsetAsync(d_out, 0, (size_t)N_GRAPHS * DIM * 4, stream);

  k_cvt_x<<<6250, 256, 0, stream>>>(x, P);
  k_cvt_w<<<384, 256, 0, stream>>>(W1, W2, WtA, WtB);

  k_count<<<(N_EDGES + 255)/256, 256, 0, stream>>>(ei, deg);
  k_scan1<<<98, 256, 0, stream>>>(deg, partial);
  k_scan2<<<1, 128, 0, stream>>>(partial, poffset, rowptr);
  k_scan3<<<98, 256, 0, stream>>>(deg, poffset, rowptr, cursor);
  k_fill<<<(N_EDGES + 255)/256, 256, 0, stream>>>(ei, cursor, colx);

  const int aggGrid = N_NODES / 4;          // 4 waves/block, 1 node/wave
  const int mlpGrid = (N_NODES + 63) / 64;  // 1563

  // layer 0: x=P, agg->Q, mlp(P,Q)->Q
  k_agg<<<aggGrid, 256, 0, stream>>>(P, Q, rowptr, colx);
  k_mlp<<<mlpGrid, 256, 0, stream>>>(P, Q, WtA + 0*16384, b1 + 0*128, WtB + 0*16384, b2 + 0*128);
  // layer 1: x=Q, agg->P, mlp(Q,P)->P
  k_agg<<<aggGrid, 256, 0, stream>>>(Q, P, rowptr, colx);
  k_mlp<<<mlpGrid, 256, 0, stream>>>(Q, P, WtA + 1*16384, b1 + 1*128, WtB + 1*16384, b2 + 1*128);
  // layer 2: x=P, agg->Q, mlp(P,Q)->Q
  k_agg<<<aggGrid, 256, 0, stream>>>(P, Q, rowptr, colx);
  k_mlp<<<mlpGrid, 256, 0, stream>>>(P, Q, WtA + 2*16384, b1 + 2*128, WtB + 2*16384, b2 + 2*128);

  k_pool<<<N_GRAPHS * 4, 256, 0, stream>>>(Q, bat, out);
}

// Round 2
// 477.866 us; speedup vs baseline: 1.3328x; 1.3328x over previous
//
#include <hip/hip_runtime.h>
#include <hip/hip_bf16.h>
#include <stdint.h>

#define N_NODES 100000
#define N_EDGES 1600000
#define DIM 128
#define N_GRAPHS 128
#define LDA 136   // padded LDS stride in bf16 elems: 272B rows -> bank step 4, 2-way max (free)

#define NBKT 196     // buckets of 512 nodes: bucket = dst >> 9
#define BCAP 12288   // per-bucket capacity (mean 8163, sigma ~90 -> 45 sigma headroom)

typedef unsigned int uint32;
typedef unsigned short ushort16;

typedef __bf16 bf16x8 __attribute__((ext_vector_type(8)));
typedef float fx4 __attribute__((ext_vector_type(4)));

__device__ __forceinline__ float bfLo(uint32 u){ return __builtin_bit_cast(float, (uint32)(u << 16)); }
__device__ __forceinline__ float bfHi(uint32 u){ return __builtin_bit_cast(float, (uint32)(u & 0xFFFF0000u)); }
__device__ __forceinline__ ushort16 f2bf(float f){
  uint32 u = __builtin_bit_cast(uint32, f);
  u = u + 0x7FFFu + ((u >> 16) & 1u);   // round-to-nearest-even
  return (ushort16)(u >> 16);
}
__device__ __forceinline__ uint32 pack2(float a, float b){
  return (uint32)f2bf(a) | ((uint32)f2bf(b) << 16);
}
__device__ __forceinline__ uint32 addpack(uint32 x, uint32 a){
  return pack2(bfLo(x)+bfLo(a), bfHi(x)+bfHi(a));
}

// ---------- conversion kernels (once per launch) ----------
__global__ __launch_bounds__(256) void k_cvt_x(const float* __restrict__ x, ushort16* __restrict__ P){
  int idx = (blockIdx.x*256 + threadIdx.x) * 8;   // 6250 blocks * 256 * 8 = 12.8M exactly
  float4 v0 = *(const float4*)(x + idx);
  float4 v1 = *(const float4*)(x + idx + 4);
  uint4 o;
  o.x = pack2(v0.x, v0.y); o.y = pack2(v0.z, v0.w);
  o.z = pack2(v1.x, v1.y); o.w = pack2(v1.z, v1.w);
  *(uint4*)(P + idx) = o;
}

// build Wt[layer][n][k] = W[layer][k][n] in bf16 (so MFMA B-frags are contiguous in k)
__global__ __launch_bounds__(256) void k_cvt_w(const float* __restrict__ W1, const float* __restrict__ W2,
                                               ushort16* __restrict__ WtA, ushort16* __restrict__ WtB){
  int idx = blockIdx.x*256 + threadIdx.x;          // 0..98303
  const float* src = (idx < 49152) ? W1 : W2;
  ushort16*    dst = (idx < 49152) ? WtA : WtB;
  int il = idx % 49152;
  int layer = il >> 14;
  int n = (il >> 7) & 127;
  int k = il & 127;
  dst[layer*16384 + n*128 + k] = f2bf(src[layer*16384 + k*128 + n]);
}

// ---------- CSR build: two-phase LDS counting sort ----------
// Phase A: block sorts 8192 edges by coarse bucket (dst>>9) in LDS, writes
// bucket-contiguous runs into fixed-capacity global bucket regions.
__global__ __launch_bounds__(512) void k_binA(const int* __restrict__ ei,
                                              int* __restrict__ bucketCursor,
                                              int* __restrict__ temp){
  __shared__ int hist[NBKT];
  __shared__ int base[NBKT];
  __shared__ int gbase[NBKT];
  __shared__ int scanbuf[256];
  __shared__ int sVal[8192];
  __shared__ unsigned short sBkt[8192];
  int t = threadIdx.x;
  int e0 = blockIdx.x * 8192;

  for (int i = t; i < NBKT; i += 512) hist[i] = 0;
  __syncthreads();

  int   myv[16];
  short myb[16];
  short myr[16];
  #pragma unroll
  for (int it = 0; it < 16; ++it){
    int e = e0 + it*512 + t;
    int v = 0; short b = -1; short r = 0;
    if (e < N_EDGES){
      int s = ei[e];
      int d = ei[N_EDGES + e];
      b = (short)(d >> 9);
      v = s | ((d & 511) << 17);
      r = (short)atomicAdd(&hist[b], 1);
    }
    myv[it] = v; myb[it] = b; myr[it] = r;
  }
  __syncthreads();

  // exclusive scan of hist (196 <= 256) + global reservation
  if (t < 256) scanbuf[t] = (t < NBKT) ? hist[t] : 0;
  __syncthreads();
  for (int off = 1; off < 256; off <<= 1){
    int x = 0;
    if (t < 256 && t >= off) x = scanbuf[t - off];
    __syncthreads();
    if (t < 256) scanbuf[t] += x;
    __syncthreads();
  }
  if (t < NBKT){
    base[t]  = scanbuf[t] - hist[t];                 // exclusive
    gbase[t] = atomicAdd(&bucketCursor[t], hist[t]); // reserve run
  }
  __syncthreads();

  #pragma unroll
  for (int it = 0; it < 16; ++it){
    if (myb[it] >= 0){
      int p = base[myb[it]] + myr[it];
      sVal[p] = myv[it];
      sBkt[p] = (unsigned short)myb[it];
    }
  }
  __syncthreads();

  int cnt = scanbuf[NBKT - 1];  // total valid edges in this block
  for (int p = t; p < cnt; p += 512){
    int b = sBkt[p];
    int g = gbase[b] + (p - base[b]);
    if (g < BCAP) temp[b*BCAP + g] = sVal[p];
  }
}

__global__ void k_scanbkt(const int* __restrict__ bucketCursor, int* __restrict__ bucketBase,
                          int* __restrict__ rowptr){
  __shared__ int s[256];
  int t = threadIdx.x;
  int v = (t < NBKT) ? min(bucketCursor[t], BCAP) : 0;
  s[t] = v; __syncthreads();
  for (int off = 1; off < 256; off <<= 1){
    int x = (t >= off) ? s[t - off] : 0; __syncthreads(); s[t] += x; __syncthreads();
  }
  if (t < NBKT) bucketBase[t] = s[t] - v;
  if (t == NBKT - 1){ bucketBase[NBKT] = s[t]; rowptr[N_NODES] = s[t]; }
}

// Phase B: one block per bucket; build the 512-node sub-CSR entirely in LDS,
// then write colx coalesced + rowptr for this bucket's node range.
__global__ __launch_bounds__(512) void k_binB(const int* __restrict__ temp,
                                              const int* __restrict__ bucketCursor,
                                              const int* __restrict__ bucketBase,
                                              int* __restrict__ rowptr,
                                              int* __restrict__ colx){
  __shared__ int counts[512];
  __shared__ int sc[512];
  __shared__ int cur[512];
  __shared__ int stage[BCAP];
  __shared__ int sorted[BCAP];
  int b = blockIdx.x, t = threadIdx.x;
  int cnt = min(bucketCursor[b], BCAP);
  int gb  = bucketBase[b];
  const int* src = temp + b*BCAP;

  counts[t] = 0;
  __syncthreads();
  for (int p = t; p < cnt; p += 512){
    int v = src[p];
    stage[p] = v;
    atomicAdd(&counts[v >> 17], 1);
  }
  __syncthreads();

  int myc = counts[t];
  sc[t] = myc; __syncthreads();
  for (int off = 1; off < 512; off <<= 1){
    int x = (t >= off) ? sc[t - off] : 0; __syncthreads(); sc[t] += x; __syncthreads();
  }
  int excl = sc[t] - myc;
  cur[t] = excl;
  int node = b*512 + t;
  if (node < N_NODES) rowptr[node] = gb + excl;
  __syncthreads();

  for (int p = t; p < cnt; p += 512){
    int v = stage[p];
    int d = v >> 17;
    int pos = atomicAdd(&cur[d], 1);
    sorted[pos] = v & 0x1FFFF;
  }
  __syncthreads();

  for (int p = t; p < cnt; p += 512) colx[gb + p] = sorted[p];
}

// ---------- aggregation: one wave per node, CSR gather, no f32 atomics ----------
__global__ __launch_bounds__(256) void k_agg(const ushort16* __restrict__ xb, ushort16* __restrict__ ob,
                                             const int* __restrict__ rowptr, const int* __restrict__ colx){
  int node = (blockIdx.x*256 + threadIdx.x) >> 6;   // 25000 blocks * 4 waves = 100000
  int lane = threadIdx.x & 63;
  int start = rowptr[node], end = rowptr[node+1];
  float a0 = 0.f, a1 = 0.f;
  int j = start;
  for (; j + 4 <= end; j += 4){
    int s0 = colx[j], s1 = colx[j+1], s2 = colx[j+2], s3 = colx[j+3];
    uint32 u0 = *(const uint32*)(xb + s0*128 + lane*2);
    uint32 u1 = *(const uint32*)(xb + s1*128 + lane*2);
    uint32 u2 = *(const uint32*)(xb + s2*128 + lane*2);
    uint32 u3 = *(const uint32*)(xb + s3*128 + lane*2);
    a0 += (bfLo(u0) + bfLo(u1)) + (bfLo(u2) + bfLo(u3));
    a1 += (bfHi(u0) + bfHi(u1)) + (bfHi(u2) + bfHi(u3));
  }
  for (; j < end; ++j){
    int sx = colx[j];
    uint32 u = *(const uint32*)(xb + sx*128 + lane*2);
    a0 += bfLo(u); a1 += bfHi(u);
  }
  *(uint32*)(ob + node*128 + lane*2) = pack2(a0, a1);
}

// ---------- fused GIN MLP: out = relu((x+agg)@W1 + b1)@W2 + b2, in-place over agg buffer ----------
__global__ __launch_bounds__(256) void k_mlp(const ushort16* __restrict__ xb, ushort16* __restrict__ hb,
                                             const ushort16* __restrict__ Wt1, const float* __restrict__ b1,
                                             const ushort16* __restrict__ Wt2, const float* __restrict__ b2){
  __shared__ __attribute__((aligned(16))) ushort16 sA[64 * LDA];   // h0 tile, later reused as h tile
  __shared__ __attribute__((aligned(16))) ushort16 sW[128 * LDA];  // W^T (bf16), W1 then W2
  int t = threadIdx.x;
  int row0 = blockIdx.x * 64;

  int sr = t >> 4;            // 0..15
  int sc = (t & 15) * 8;      // 0,8,...,120

  // stage sA = x + agg (bf16), zeros for OOB rows
  #pragma unroll
  for (int it = 0; it < 4; ++it){
    int row = it*16 + sr;
    int g = row0 + row;
    uint4 o;
    if (g < N_NODES){
      uint4 xv = *(const uint4*)(xb + g*128 + sc);
      uint4 av = *(const uint4*)(hb + g*128 + sc);
      o.x = addpack(xv.x, av.x); o.y = addpack(xv.y, av.y);
      o.z = addpack(xv.z, av.z); o.w = addpack(xv.w, av.w);
    } else { o.x = o.y = o.z = o.w = 0u; }
    *(uint4*)(sA + row*LDA + sc) = o;
  }
  // stage sW = W1^T
  #pragma unroll
  for (int it = 0; it < 8; ++it){
    int row = it*16 + sr;
    *(uint4*)(sW + row*LDA + sc) = *(const uint4*)(Wt1 + row*128 + sc);
  }
  __syncthreads();

  int wave = t >> 6, l = t & 63, m = l & 15, kg = l >> 4;
  fx4 acc[8];
  #pragma unroll
  for (int nt = 0; nt < 8; ++nt) acc[nt] = (fx4){0.f,0.f,0.f,0.f};

  const ushort16* aBase = sA + (wave*16 + m)*LDA + kg*8;
  const ushort16* bBase = sW + m*LDA + kg*8;

  // GEMM1
  #pragma unroll
  for (int kt = 0; kt < 4; ++kt){
    bf16x8 av = *(const bf16x8*)(aBase + kt*32);
    #pragma unroll
    for (int nt = 0; nt < 8; ++nt){
      bf16x8 bv = *(const bf16x8*)(bBase + nt*16*LDA + kt*32);
      acc[nt] = __builtin_amdgcn_mfma_f32_16x16x32_bf16(av, bv, acc[nt], 0, 0, 0);
    }
  }
  __syncthreads();   // all reads of sA/sW done

  // h = relu(acc + b1) -> sA (C-layout: col = m + 16*nt, row = kg*4 + r)
  #pragma unroll
  for (int nt = 0; nt < 8; ++nt){
    float bv = b1[nt*16 + m];
    #pragma unroll
    for (int r = 0; r < 4; ++r){
      float v = acc[nt][r] + bv;
      v = fmaxf(v, 0.f);
      sA[(wave*16 + kg*4 + r)*LDA + nt*16 + m] = f2bf(v);
    }
  }
  // stage sW = W2^T
  #pragma unroll
  for (int it = 0; it < 8; ++it){
    int row = it*16 + sr;
    *(uint4*)(sW + row*LDA + sc) = *(const uint4*)(Wt2 + row*128 + sc);
  }
  __syncthreads();

  #pragma unroll
  for (int nt = 0; nt < 8; ++nt) acc[nt] = (fx4){0.f,0.f,0.f,0.f};

  // GEMM2
  #pragma unroll
  for (int kt = 0; kt < 4; ++kt){
    bf16x8 av = *(const bf16x8*)(aBase + kt*32);
    #pragma unroll
    for (int nt = 0; nt < 8; ++nt){
      bf16x8 bv = *(const bf16x8*)(bBase + nt*16*LDA + kt*32);
      acc[nt] = __builtin_amdgcn_mfma_f32_16x16x32_bf16(av, bv, acc[nt], 0, 0, 0);
    }
  }

  // epilogue: out = acc + b2 -> hb (bf16), same rows this block consumed (in-place safe)
  #pragma unroll
  for (int nt = 0; nt < 8; ++nt){
    float bv = b2[nt*16 + m];
    #pragma unroll
    for (int r = 0; r < 4; ++r){
      int g = row0 + wave*16 + kg*4 + r;
      if (g < N_NODES){
        float v = acc[nt][r] + bv;
        hb[g*128 + nt*16 + m] = f2bf(v);
      }
    }
  }
}

// ---------- sum-pool per graph (batch sorted) ----------
__device__ __forceinline__ int lower_bound_i(const int* __restrict__ a, int n, int key){
  int lo = 0, hi = n;
  while (lo < hi){ int mid = (lo + hi) >> 1; if (a[mid] < key) lo = mid + 1; else hi = mid; }
  return lo;
}

__global__ __launch_bounds__(256) void k_pool(const ushort16* __restrict__ xb, const int* __restrict__ batch,
                                              float* __restrict__ out){
  int g = blockIdx.x >> 2;
  int p = blockIdx.x & 3;
  int start = lower_bound_i(batch, N_NODES, g);
  int end   = lower_bound_i(batch, N_NODES, g + 1);
  int t = threadIdx.x;
  int c = t & 127;
  int h = t >> 7;
  float acc = 0.f;
  for (int r = start + p*2 + h; r < end; r += 8){
    uint32 u = (uint32)xb[r*128 + c];
    acc += __builtin_bit_cast(float, (uint32)(u << 16));
  }
  __shared__ float red[256];
  red[t] = acc; __syncthreads();
  if (t < 128) atomicAdd(&out[g*128 + c], red[t] + red[t + 128]);
}

// ---------- launch ----------
extern "C" void kernel_launch(void* const* d_in, const int* in_sizes, int n_in,
                              void* d_out, int out_size, void* d_ws, size_t ws_size,
                              hipStream_t stream) {
  const float* x   = (const float*)d_in[0];
  const float* W1  = (const float*)d_in[1];
  const float* b1  = (const float*)d_in[2];
  const float* W2  = (const float*)d_in[3];
  const float* b2  = (const float*)d_in[4];
  const int*   ei  = (const int*)d_in[5];
  const int*   bat = (const int*)d_in[6];
  float* out = (float*)d_out;

  char* w = (char*)d_ws;
  auto carve = [&](size_t bytes) -> char* {
    char* p = w; w += (bytes + 255) & ~(size_t)255; return p;
  };
  ushort16* P    = (ushort16*)carve((size_t)N_NODES * DIM * 2);
  ushort16* Q    = (ushort16*)carve((size_t)N_NODES * DIM * 2);
  ushort16* WtA  = (ushort16*)carve(3 * 16384 * 2);
  ushort16* WtB  = (ushort16*)carve(3 * 16384 * 2);
  int* rowptr    = (int*)carve((size_t)(N_NODES + 1) * 4);
  int* colx      = (int*)carve((size_t)N_EDGES * 4);
  int* bucketCursor = (int*)carve((NBKT + 1) * 4);
  int* bucketBase   = (int*)carve((NBKT + 1) * 4);
  // temp bucket regions alias Q: only live during CSR build, before first k_agg write
  int* temp      = (int*)Q;   // NBKT*BCAP*4 = 9.63 MB <= 25.6 MB

  hipMemsetAsync(bucketCursor, 0, (NBKT + 1) * 4, stream);
  hipMemsetAsync(d_out, 0, (size_t)N_GRAPHS * DIM * 4, stream);

  k_cvt_x<<<6250, 256, 0, stream>>>(x, P);
  k_cvt_w<<<384, 256, 0, stream>>>(W1, W2, WtA, WtB);

  k_binA<<<(N_EDGES + 8191)/8192, 512, 0, stream>>>(ei, bucketCursor, temp);
  k_scanbkt<<<1, 256, 0, stream>>>(bucketCursor, bucketBase, rowptr);
  k_binB<<<NBKT, 512, 0, stream>>>(temp, bucketCursor, bucketBase, rowptr, colx);

  const int aggGrid = N_NODES / 4;          // 4 waves/block, 1 node/wave
  const int mlpGrid = (N_NODES + 63) / 64;  // 1563

  // layer 0: x=P, agg->Q, mlp(P,Q)->Q
  k_agg<<<aggGrid, 256, 0, stream>>>(P, Q, rowptr, colx);
  k_mlp<<<mlpGrid, 256, 0, stream>>>(P, Q, WtA + 0*16384, b1 + 0*128, WtB + 0*16384, b2 + 0*128);
  // layer 1: x=Q, agg->P, mlp(Q,P)->P
  k_agg<<<aggGrid, 256, 0, stream>>>(Q, P, rowptr, colx);
  k_mlp<<<mlpGrid, 256, 0, stream>>>(Q, P, WtA + 1*16384, b1 + 1*128, WtB + 1*16384, b2 + 1*128);
  // layer 2: x=P, agg->Q, mlp(P,Q)->Q
  k_agg<<<aggGrid, 256, 0, stream>>>(P, Q, rowptr, colx);
  k_mlp<<<mlpGrid, 256, 0, stream>>>(P, Q, WtA + 2*16384, b1 + 2*128, WtB + 2*16384, b2 + 2*128);

  k_pool<<<N_GRAPHS * 4, 256, 0, stream>>>(Q, bat, out);
}

// Round 3
// 458.008 us; speedup vs baseline: 1.3906x; 1.0434x over previous
//
#include <hip/hip_runtime.h>
#include <hip/hip_bf16.h>
#include <stdint.h>

#define N_NODES 100000
#define N_EDGES 1600000
#define DIM 128
#define N_GRAPHS 128
#define LDA 136   // padded LDS stride in bf16 elems: 272B rows -> bank step 4, 2-way max (free)

#define NBKT 196     // buckets of 512 nodes: bucket = dst >> 9
#define BCAP 12288   // per-bucket capacity (mean 8163, sigma ~90 -> 45 sigma headroom)

typedef unsigned int uint32;
typedef unsigned short ushort16;

typedef __bf16 bf16x8 __attribute__((ext_vector_type(8)));
typedef float fx4 __attribute__((ext_vector_type(4)));

__device__ __forceinline__ float bfLo(uint32 u){ return __builtin_bit_cast(float, (uint32)(u << 16)); }
__device__ __forceinline__ float bfHi(uint32 u){ return __builtin_bit_cast(float, (uint32)(u & 0xFFFF0000u)); }
__device__ __forceinline__ ushort16 f2bf(float f){
  uint32 u = __builtin_bit_cast(uint32, f);
  u = u + 0x7FFFu + ((u >> 16) & 1u);   // round-to-nearest-even
  return (ushort16)(u >> 16);
}
__device__ __forceinline__ uint32 pack2(float a, float b){
  return (uint32)f2bf(a) | ((uint32)f2bf(b) << 16);
}
__device__ __forceinline__ uint32 addpack(uint32 x, uint32 a){
  return pack2(bfLo(x)+bfLo(a), bfHi(x)+bfHi(a));
}

// ---------- conversion kernels (once per launch) ----------
__global__ __launch_bounds__(256) void k_cvt_x(const float* __restrict__ x, ushort16* __restrict__ P){
  int idx = (blockIdx.x*256 + threadIdx.x) * 8;   // 6250 blocks * 256 * 8 = 12.8M exactly
  float4 v0 = *(const float4*)(x + idx);
  float4 v1 = *(const float4*)(x + idx + 4);
  uint4 o;
  o.x = pack2(v0.x, v0.y); o.y = pack2(v0.z, v0.w);
  o.z = pack2(v1.x, v1.y); o.w = pack2(v1.z, v1.w);
  *(uint4*)(P + idx) = o;
}

// build Wt[layer][n][k] = W[layer][k][n] in bf16 (so MFMA B-frags are contiguous in k)
__global__ __launch_bounds__(256) void k_cvt_w(const float* __restrict__ W1, const float* __restrict__ W2,
                                               ushort16* __restrict__ WtA, ushort16* __restrict__ WtB){
  int idx = blockIdx.x*256 + threadIdx.x;          // 0..98303
  const float* src = (idx < 49152) ? W1 : W2;
  ushort16*    dst = (idx < 49152) ? WtA : WtB;
  int il = idx % 49152;
  int layer = il >> 14;
  int n = (il >> 7) & 127;
  int k = il & 127;
  dst[layer*16384 + n*128 + k] = f2bf(src[layer*16384 + k*128 + n]);
}

// ---------- CSR build: two-phase LDS counting sort ----------
// Phase A: block sorts 8192 edges by coarse bucket (dst>>9) in LDS, writes
// bucket-contiguous runs into fixed-capacity global bucket regions.
__global__ __launch_bounds__(512) void k_binA(const int* __restrict__ ei,
                                              int* __restrict__ bucketCursor,
                                              int* __restrict__ temp){
  __shared__ int hist[NBKT];
  __shared__ int base[NBKT];
  __shared__ int gbase[NBKT];
  __shared__ int scanbuf[256];
  __shared__ int sVal[8192];
  __shared__ unsigned short sBkt[8192];
  int t = threadIdx.x;
  int e0 = blockIdx.x * 8192;

  for (int i = t; i < NBKT; i += 512) hist[i] = 0;
  __syncthreads();

  int   myv[16];
  short myb[16];
  short myr[16];
  #pragma unroll
  for (int it = 0; it < 16; ++it){
    int e = e0 + it*512 + t;
    int v = 0; short b = -1; short r = 0;
    if (e < N_EDGES){
      int s = ei[e];
      int d = ei[N_EDGES + e];
      b = (short)(d >> 9);
      v = s | ((d & 511) << 17);
      r = (short)atomicAdd(&hist[b], 1);
    }
    myv[it] = v; myb[it] = b; myr[it] = r;
  }
  __syncthreads();

  // exclusive scan of hist (196 <= 256) + global reservation
  if (t < 256) scanbuf[t] = (t < NBKT) ? hist[t] : 0;
  __syncthreads();
  for (int off = 1; off < 256; off <<= 1){
    int x = 0;
    if (t < 256 && t >= off) x = scanbuf[t - off];
    __syncthreads();
    if (t < 256) scanbuf[t] += x;
    __syncthreads();
  }
  if (t < NBKT){
    base[t]  = scanbuf[t] - hist[t];                 // exclusive
    gbase[t] = atomicAdd(&bucketCursor[t], hist[t]); // reserve run
  }
  __syncthreads();

  #pragma unroll
  for (int it = 0; it < 16; ++it){
    if (myb[it] >= 0){
      int p = base[myb[it]] + myr[it];
      sVal[p] = myv[it];
      sBkt[p] = (unsigned short)myb[it];
    }
  }
  __syncthreads();

  int cnt = scanbuf[NBKT - 1];  // total valid edges in this block
  for (int p = t; p < cnt; p += 512){
    int b = sBkt[p];
    int g = gbase[b] + (p - base[b]);
    if (g < BCAP) temp[b*BCAP + g] = sVal[p];
  }
}

__global__ void k_scanbkt(const int* __restrict__ bucketCursor, int* __restrict__ bucketBase,
                          int* __restrict__ rowptr){
  __shared__ int s[256];
  int t = threadIdx.x;
  int v = (t < NBKT) ? min(bucketCursor[t], BCAP) : 0;
  s[t] = v; __syncthreads();
  for (int off = 1; off < 256; off <<= 1){
    int x = (t >= off) ? s[t - off] : 0; __syncthreads(); s[t] += x; __syncthreads();
  }
  if (t < NBKT) bucketBase[t] = s[t] - v;
  if (t == NBKT - 1){ bucketBase[NBKT] = s[t]; rowptr[N_NODES] = s[t]; }
}

// Phase B: one block per bucket; build the 512-node sub-CSR entirely in LDS,
// then write colx coalesced + rowptr for this bucket's node range.
__global__ __launch_bounds__(512) void k_binB(const int* __restrict__ temp,
                                              const int* __restrict__ bucketCursor,
                                              const int* __restrict__ bucketBase,
                                              int* __restrict__ rowptr,
                                              int* __restrict__ colx){
  __shared__ int counts[512];
  __shared__ int sc[512];
  __shared__ int cur[512];
  __shared__ int stage[BCAP];
  __shared__ int sorted[BCAP];
  int b = blockIdx.x, t = threadIdx.x;
  int cnt = min(bucketCursor[b], BCAP);
  int gb  = bucketBase[b];
  const int* src = temp + b*BCAP;

  counts[t] = 0;
  __syncthreads();
  for (int p = t; p < cnt; p += 512){
    int v = src[p];
    stage[p] = v;
    atomicAdd(&counts[v >> 17], 1);
  }
  __syncthreads();

  int myc = counts[t];
  sc[t] = myc; __syncthreads();
  for (int off = 1; off < 512; off <<= 1){
    int x = (t >= off) ? sc[t - off] : 0; __syncthreads(); sc[t] += x; __syncthreads();
  }
  int excl = sc[t] - myc;
  cur[t] = excl;
  int node = b*512 + t;
  if (node < N_NODES) rowptr[node] = gb + excl;
  __syncthreads();

  for (int p = t; p < cnt; p += 512){
    int v = stage[p];
    int d = v >> 17;
    int pos = atomicAdd(&cur[d], 1);
    sorted[pos] = v & 0x1FFFF;
  }
  __syncthreads();

  for (int p = t; p < cnt; p += 512) colx[gb + p] = sorted[p];
}

// ---------- aggregation: one wave per TWO nodes, interleaved for 2x MLP ----------
// Latency-bound fix (R3): 8 independent 256B row-loads in flight per wave
// (two independent accumulate chains), half the wave churn.
__global__ __launch_bounds__(256) void k_agg(const ushort16* __restrict__ xb, ushort16* __restrict__ ob,
                                             const int* __restrict__ rowptr, const int* __restrict__ colx){
  int w = (blockIdx.x*256 + threadIdx.x) >> 6;   // 12500 blocks * 4 waves = 50000
  int lane = threadIdx.x & 63;
  int nA = w;
  int nB = w + (N_NODES/2);
  int ja = rowptr[nA], ea = rowptr[nA+1];
  int jb = rowptr[nB], eb = rowptr[nB+1];
  float a0 = 0.f, a1 = 0.f;
  float b0 = 0.f, b1 = 0.f;

  // joint loop: 4 edges per node per iteration -> 8 row loads in flight
  while (ja + 4 <= ea && jb + 4 <= eb){
    int as0 = colx[ja], as1 = colx[ja+1], as2 = colx[ja+2], as3 = colx[ja+3];
    int bs0 = colx[jb], bs1 = colx[jb+1], bs2 = colx[jb+2], bs3 = colx[jb+3];
    uint32 ua0 = *(const uint32*)(xb + as0*128 + lane*2);
    uint32 ua1 = *(const uint32*)(xb + as1*128 + lane*2);
    uint32 ua2 = *(const uint32*)(xb + as2*128 + lane*2);
    uint32 ua3 = *(const uint32*)(xb + as3*128 + lane*2);
    uint32 ub0 = *(const uint32*)(xb + bs0*128 + lane*2);
    uint32 ub1 = *(const uint32*)(xb + bs1*128 + lane*2);
    uint32 ub2 = *(const uint32*)(xb + bs2*128 + lane*2);
    uint32 ub3 = *(const uint32*)(xb + bs3*128 + lane*2);
    a0 += (bfLo(ua0) + bfLo(ua1)) + (bfLo(ua2) + bfLo(ua3));
    a1 += (bfHi(ua0) + bfHi(ua1)) + (bfHi(ua2) + bfHi(ua3));
    b0 += (bfLo(ub0) + bfLo(ub1)) + (bfLo(ub2) + bfLo(ub3));
    b1 += (bfHi(ub0) + bfHi(ub1)) + (bfHi(ub2) + bfHi(ub3));
    ja += 4; jb += 4;
  }
  // remainder for node A (4-unroll then scalar)
  for (; ja + 4 <= ea; ja += 4){
    int s0 = colx[ja], s1 = colx[ja+1], s2 = colx[ja+2], s3 = colx[ja+3];
    uint32 u0 = *(const uint32*)(xb + s0*128 + lane*2);
    uint32 u1 = *(const uint32*)(xb + s1*128 + lane*2);
    uint32 u2 = *(const uint32*)(xb + s2*128 + lane*2);
    uint32 u3 = *(const uint32*)(xb + s3*128 + lane*2);
    a0 += (bfLo(u0) + bfLo(u1)) + (bfLo(u2) + bfLo(u3));
    a1 += (bfHi(u0) + bfHi(u1)) + (bfHi(u2) + bfHi(u3));
  }
  for (; ja < ea; ++ja){
    uint32 u = *(const uint32*)(xb + colx[ja]*128 + lane*2);
    a0 += bfLo(u); a1 += bfHi(u);
  }
  // remainder for node B
  for (; jb + 4 <= eb; jb += 4){
    int s0 = colx[jb], s1 = colx[jb+1], s2 = colx[jb+2], s3 = colx[jb+3];
    uint32 u0 = *(const uint32*)(xb + s0*128 + lane*2);
    uint32 u1 = *(const uint32*)(xb + s1*128 + lane*2);
    uint32 u2 = *(const uint32*)(xb + s2*128 + lane*2);
    uint32 u3 = *(const uint32*)(xb + s3*128 + lane*2);
    b0 += (bfLo(u0) + bfLo(u1)) + (bfLo(u2) + bfLo(u3));
    b1 += (bfHi(u0) + bfHi(u1)) + (bfHi(u2) + bfHi(u3));
  }
  for (; jb < eb; ++jb){
    uint32 u = *(const uint32*)(xb + colx[jb]*128 + lane*2);
    b0 += bfLo(u); b1 += bfHi(u);
  }

  *(uint32*)(ob + nA*128 + lane*2) = pack2(a0, a1);
  *(uint32*)(ob + nB*128 + lane*2) = pack2(b0, b1);
}

// ---------- fused GIN MLP: out = relu((x+agg)@W1 + b1)@W2 + b2, in-place over agg buffer ----------
__global__ __launch_bounds__(256) void k_mlp(const ushort16* __restrict__ xb, ushort16* __restrict__ hb,
                                             const ushort16* __restrict__ Wt1, const float* __restrict__ b1,
                                             const ushort16* __restrict__ Wt2, const float* __restrict__ b2){
  __shared__ __attribute__((aligned(16))) ushort16 sA[64 * LDA];   // h0 tile, later reused as h tile
  __shared__ __attribute__((aligned(16))) ushort16 sW[128 * LDA];  // W^T (bf16), W1 then W2
  int t = threadIdx.x;
  int row0 = blockIdx.x * 64;

  int sr = t >> 4;            // 0..15
  int sc = (t & 15) * 8;      // 0,8,...,120

  // stage sA = x + agg (bf16), zeros for OOB rows
  #pragma unroll
  for (int it = 0; it < 4; ++it){
    int row = it*16 + sr;
    int g = row0 + row;
    uint4 o;
    if (g < N_NODES){
      uint4 xv = *(const uint4*)(xb + g*128 + sc);
      uint4 av = *(const uint4*)(hb + g*128 + sc);
      o.x = addpack(xv.x, av.x); o.y = addpack(xv.y, av.y);
      o.z = addpack(xv.z, av.z); o.w = addpack(xv.w, av.w);
    } else { o.x = o.y = o.z = o.w = 0u; }
    *(uint4*)(sA + row*LDA + sc) = o;
  }
  // stage sW = W1^T
  #pragma unroll
  for (int it = 0; it < 8; ++it){
    int row = it*16 + sr;
    *(uint4*)(sW + row*LDA + sc) = *(const uint4*)(Wt1 + row*128 + sc);
  }
  __syncthreads();

  int wave = t >> 6, l = t & 63, m = l & 15, kg = l >> 4;
  fx4 acc[8];
  #pragma unroll
  for (int nt = 0; nt < 8; ++nt) acc[nt] = (fx4){0.f,0.f,0.f,0.f};

  const ushort16* aBase = sA + (wave*16 + m)*LDA + kg*8;
  const ushort16* bBase = sW + m*LDA + kg*8;

  // GEMM1
  #pragma unroll
  for (int kt = 0; kt < 4; ++kt){
    bf16x8 av = *(const bf16x8*)(aBase + kt*32);
    #pragma unroll
    for (int nt = 0; nt < 8; ++nt){
      bf16x8 bv = *(const bf16x8*)(bBase + nt*16*LDA + kt*32);
      acc[nt] = __builtin_amdgcn_mfma_f32_16x16x32_bf16(av, bv, acc[nt], 0, 0, 0);
    }
  }
  __syncthreads();   // all reads of sA/sW done

  // h = relu(acc + b1) -> sA (C-layout: col = m + 16*nt, row = kg*4 + r)
  #pragma unroll
  for (int nt = 0; nt < 8; ++nt){
    float bv = b1[nt*16 + m];
    #pragma unroll
    for (int r = 0; r < 4; ++r){
      float v = acc[nt][r] + bv;
      v = fmaxf(v, 0.f);
      sA[(wave*16 + kg*4 + r)*LDA + nt*16 + m] = f2bf(v);
    }
  }
  // stage sW = W2^T
  #pragma unroll
  for (int it = 0; it < 8; ++it){
    int row = it*16 + sr;
    *(uint4*)(sW + row*LDA + sc) = *(const uint4*)(Wt2 + row*128 + sc);
  }
  __syncthreads();

  #pragma unroll
  for (int nt = 0; nt < 8; ++nt) acc[nt] = (fx4){0.f,0.f,0.f,0.f};

  // GEMM2
  #pragma unroll
  for (int kt = 0; kt < 4; ++kt){
    bf16x8 av = *(const bf16x8*)(aBase + kt*32);
    #pragma unroll
    for (int nt = 0; nt < 8; ++nt){
      bf16x8 bv = *(const bf16x8*)(bBase + nt*16*LDA + kt*32);
      acc[nt] = __builtin_amdgcn_mfma_f32_16x16x32_bf16(av, bv, acc[nt], 0, 0, 0);
    }
  }

  // epilogue: out = acc + b2 -> hb (bf16), same rows this block consumed (in-place safe)
  #pragma unroll
  for (int nt = 0; nt < 8; ++nt){
    float bv = b2[nt*16 + m];
    #pragma unroll
    for (int r = 0; r < 4; ++r){
      int g = row0 + wave*16 + kg*4 + r;
      if (g < N_NODES){
        float v = acc[nt][r] + bv;
        hb[g*128 + nt*16 + m] = f2bf(v);
      }
    }
  }
}

// ---------- sum-pool per graph (batch sorted) ----------
__device__ __forceinline__ int lower_bound_i(const int* __restrict__ a, int n, int key){
  int lo = 0, hi = n;
  while (lo < hi){ int mid = (lo + hi) >> 1; if (a[mid] < key) lo = mid + 1; else hi = mid; }
  return lo;
}

__global__ __launch_bounds__(256) void k_pool(const ushort16* __restrict__ xb, const int* __restrict__ batch,
                                              float* __restrict__ out){
  int g = blockIdx.x >> 2;
  int p = blockIdx.x & 3;
  int start = lower_bound_i(batch, N_NODES, g);
  int end   = lower_bound_i(batch, N_NODES, g + 1);
  int t = threadIdx.x;
  int c = t & 127;
  int h = t >> 7;
  float acc = 0.f;
  for (int r = start + p*2 + h; r < end; r += 8){
    uint32 u = (uint32)xb[r*128 + c];
    acc += __builtin_bit_cast(float, (uint32)(u << 16));
  }
  __shared__ float red[256];
  red[t] = acc; __syncthreads();
  if (t < 128) atomicAdd(&out[g*128 + c], red[t] + red[t + 128]);
}

// ---------- launch ----------
extern "C" void kernel_launch(void* const* d_in, const int* in_sizes, int n_in,
                              void* d_out, int out_size, void* d_ws, size_t ws_size,
                              hipStream_t stream) {
  const float* x   = (const float*)d_in[0];
  const float* W1  = (const float*)d_in[1];
  const float* b1  = (const float*)d_in[2];
  const float* W2  = (const float*)d_in[3];
  const float* b2  = (const float*)d_in[4];
  const int*   ei  = (const int*)d_in[5];
  const int*   bat = (const int*)d_in[6];
  float* out = (float*)d_out;

  char* w = (char*)d_ws;
  auto carve = [&](size_t bytes) -> char* {
    char* p = w; w += (bytes + 255) & ~(size_t)255; return p;
  };
  ushort16* P    = (ushort16*)carve((size_t)N_NODES * DIM * 2);
  ushort16* Q    = (ushort16*)carve((size_t)N_NODES * DIM * 2);
  ushort16* WtA  = (ushort16*)carve(3 * 16384 * 2);
  ushort16* WtB  = (ushort16*)carve(3 * 16384 * 2);
  int* rowptr    = (int*)carve((size_t)(N_NODES + 1) * 4);
  int* colx      = (int*)carve((size_t)N_EDGES * 4);
  int* bucketCursor = (int*)carve((NBKT + 1) * 4);
  int* bucketBase   = (int*)carve((NBKT + 1) * 4);
  // temp bucket regions alias Q: only live during CSR build, before first k_agg write
  int* temp      = (int*)Q;   // NBKT*BCAP*4 = 9.63 MB <= 25.6 MB

  hipMemsetAsync(bucketCursor, 0, (NBKT + 1) * 4, stream);
  hipMemsetAsync(d_out, 0, (size_t)N_GRAPHS * DIM * 4, stream);

  k_cvt_x<<<6250, 256, 0, stream>>>(x, P);
  k_cvt_w<<<384, 256, 0, stream>>>(W1, W2, WtA, WtB);

  k_binA<<<(N_EDGES + 8191)/8192, 512, 0, stream>>>(ei, bucketCursor, temp);
  k_scanbkt<<<1, 256, 0, stream>>>(bucketCursor, bucketBase, rowptr);
  k_binB<<<NBKT, 512, 0, stream>>>(temp, bucketCursor, bucketBase, rowptr, colx);

  const int aggGrid = (N_NODES/2) / 4;      // 4 waves/block, 2 nodes/wave -> 12500 blocks
  const int mlpGrid = (N_NODES + 63) / 64;  // 1563

  // layer 0: x=P, agg->Q, mlp(P,Q)->Q
  k_agg<<<aggGrid, 256, 0, stream>>>(P, Q, rowptr, colx);
  k_mlp<<<mlpGrid, 256, 0, stream>>>(P, Q, WtA + 0*16384, b1 + 0*128, WtB + 0*16384, b2 + 0*128);
  // layer 1: x=Q, agg->P, mlp(Q,P)->P
  k_agg<<<aggGrid, 256, 0, stream>>>(Q, P, rowptr, colx);
  k_mlp<<<mlpGrid, 256, 0, stream>>>(Q, P, WtA + 1*16384, b1 + 1*128, WtB + 1*16384, b2 + 1*128);
  // layer 2: x=P, agg->Q, mlp(P,Q)->Q
  k_agg<<<aggGrid, 256, 0, stream>>>(P, Q, rowptr, colx);
  k_mlp<<<mlpGrid, 256, 0, stream>>>(P, Q, WtA + 2*16384, b1 + 2*128, WtB + 2*16384, b2 + 2*128);

  k_pool<<<N_GRAPHS * 4, 256, 0, stream>>>(Q, bat, out);
}

// Round 4
// 440.701 us; speedup vs baseline: 1.4452x; 1.0393x over previous
//
#include <hip/hip_runtime.h>
#include <hip/hip_bf16.h>
#include <stdint.h>

#define N_NODES 100000
#define N_EDGES 1600000
#define DIM 128
#define N_GRAPHS 128
#define LDA 136   // padded LDS stride in bf16 elems (k_mlp)

#define NBKT 196     // buckets of 512 nodes: bucket = dst >> 9
#define BCAP 12288   // per-bucket temp capacity (mean 8163, sigma ~90)
#define BP   10240   // per-bucket padded colx capacity (mult of 4; max padded ~10061)

typedef unsigned int uint32;
typedef unsigned short ushort16;

typedef __bf16 bf16x8 __attribute__((ext_vector_type(8)));
typedef float fx4 __attribute__((ext_vector_type(4)));

__device__ __forceinline__ float bfLo(uint32 u){ return __builtin_bit_cast(float, (uint32)(u << 16)); }
__device__ __forceinline__ float bfHi(uint32 u){ return __builtin_bit_cast(float, (uint32)(u & 0xFFFF0000u)); }
__device__ __forceinline__ ushort16 f2bf(float f){
  uint32 u = __builtin_bit_cast(uint32, f);
  u = u + 0x7FFFu + ((u >> 16) & 1u);   // round-to-nearest-even
  return (ushort16)(u >> 16);
}
__device__ __forceinline__ uint32 pack2(float a, float b){
  return (uint32)f2bf(a) | ((uint32)f2bf(b) << 16);
}
__device__ __forceinline__ uint32 addpack(uint32 x, uint32 a){
  return pack2(bfLo(x)+bfLo(a), bfHi(x)+bfHi(a));
}

// ---------- conversion (once per launch); block 6250 zeros the pad row in P and Q ----------
__global__ __launch_bounds__(256) void k_cvt_x(const float* __restrict__ x, ushort16* __restrict__ P,
                                               ushort16* __restrict__ Q){
  if (blockIdx.x == 6250){
    int t = threadIdx.x;
    uint4 z = {0u,0u,0u,0u};
    if (t < 16)                *(uint4*)(P + (size_t)N_NODES*128 + t*8)      = z;
    else if (t < 32)           *(uint4*)(Q + (size_t)N_NODES*128 + (t-16)*8) = z;
    return;
  }
  int idx = (blockIdx.x*256 + threadIdx.x) * 8;   // 6250 blocks * 256 * 8 = 12.8M exactly
  float4 v0 = *(const float4*)(x + idx);
  float4 v1 = *(const float4*)(x + idx + 4);
  uint4 o;
  o.x = pack2(v0.x, v0.y); o.y = pack2(v0.z, v0.w);
  o.z = pack2(v1.x, v1.y); o.w = pack2(v1.z, v1.w);
  *(uint4*)(P + idx) = o;
}

// build Wt[layer][n][k] = W[layer][k][n] in bf16 (so MFMA B-frags are contiguous in k)
__global__ __launch_bounds__(256) void k_cvt_w(const float* __restrict__ W1, const float* __restrict__ W2,
                                               ushort16* __restrict__ WtA, ushort16* __restrict__ WtB){
  int idx = blockIdx.x*256 + threadIdx.x;          // 0..98303
  const float* src = (idx < 49152) ? W1 : W2;
  ushort16*    dst = (idx < 49152) ? WtA : WtB;
  int il = idx % 49152;
  int layer = il >> 14;
  int n = (il >> 7) & 127;
  int k = il & 127;
  dst[layer*16384 + n*128 + k] = f2bf(src[layer*16384 + k*128 + n]);
}

// ---------- CSR build: two-phase LDS counting sort ----------
__global__ __launch_bounds__(512) void k_binA(const int* __restrict__ ei,
                                              int* __restrict__ bucketCursor,
                                              int* __restrict__ temp){
  __shared__ int hist[NBKT];
  __shared__ int base[NBKT];
  __shared__ int gbase[NBKT];
  __shared__ int scanbuf[256];
  __shared__ int sVal[8192];
  __shared__ unsigned short sBkt[8192];
  int t = threadIdx.x;
  int e0 = blockIdx.x * 8192;

  for (int i = t; i < NBKT; i += 512) hist[i] = 0;
  __syncthreads();

  int   myv[16];
  short myb[16];
  short myr[16];
  #pragma unroll
  for (int it = 0; it < 16; ++it){
    int e = e0 + it*512 + t;
    int v = 0; short b = -1; short r = 0;
    if (e < N_EDGES){
      int s = ei[e];
      int d = ei[N_EDGES + e];
      b = (short)(d >> 9);
      v = s | ((d & 511) << 17);
      r = (short)atomicAdd(&hist[b], 1);
    }
    myv[it] = v; myb[it] = b; myr[it] = r;
  }
  __syncthreads();

  if (t < 256) scanbuf[t] = (t < NBKT) ? hist[t] : 0;
  __syncthreads();
  for (int off = 1; off < 256; off <<= 1){
    int x = 0;
    if (t < 256 && t >= off) x = scanbuf[t - off];
    __syncthreads();
    if (t < 256) scanbuf[t] += x;
    __syncthreads();
  }
  if (t < NBKT){
    base[t]  = scanbuf[t] - hist[t];                 // exclusive
    gbase[t] = atomicAdd(&bucketCursor[t], hist[t]); // reserve run
  }
  __syncthreads();

  #pragma unroll
  for (int it = 0; it < 16; ++it){
    if (myb[it] >= 0){
      int p = base[myb[it]] + myr[it];
      sVal[p] = myv[it];
      sBkt[p] = (unsigned short)myb[it];
    }
  }
  __syncthreads();

  int cnt = scanbuf[NBKT - 1];
  for (int p = t; p < cnt; p += 512){
    int b = sBkt[p];
    int g = gbase[b] + (p - base[b]);
    if (g < BCAP) temp[b*BCAP + g] = sVal[p];
  }
}

// Phase B: one block per bucket; build 512-node sub-CSR in LDS with per-node
// padding to multiple-of-4 (pad slots -> zero row N_NODES); coalesced colx write.
__global__ __launch_bounds__(512) void k_binB(const int* __restrict__ temp,
                                              const int* __restrict__ bucketCursor,
                                              int* __restrict__ rowptr,
                                              int* __restrict__ rowlen,
                                              int* __restrict__ colx){
  __shared__ int counts[512];
  __shared__ int sc[512];
  __shared__ int cur[512];
  __shared__ int stage[BCAP];
  __shared__ int sorted[BCAP];
  int b = blockIdx.x, t = threadIdx.x;
  int cnt = min(bucketCursor[b], BCAP);
  int gb  = b * BP;
  const int* src = temp + b*BCAP;

  counts[t] = 0;
  __syncthreads();
  for (int p = t; p < cnt; p += 512){
    int v = src[p];
    stage[p] = v;
    atomicAdd(&counts[v >> 17], 1);
  }
  __syncthreads();

  int len  = counts[t];
  int plen = (len + 3) & ~3;          // padded to multiple of 4
  sc[t] = plen; __syncthreads();
  for (int off = 1; off < 512; off <<= 1){
    int x = (t >= off) ? sc[t - off] : 0; __syncthreads(); sc[t] += x; __syncthreads();
  }
  int excl = sc[t] - plen;
  cur[t] = excl;
  int node = b*512 + t;
  if (node < N_NODES){ rowptr[node] = gb + excl; rowlen[node] = plen; }
  __syncthreads();

  for (int p = t; p < cnt; p += 512){
    int v = stage[p];
    int d = v >> 17;
    int pos = atomicAdd(&cur[d], 1);
    sorted[pos] = v & 0x1FFFF;
  }
  __syncthreads();

  // pad fill: each thread pads its own node (<=3 slots) with the zero row
  for (int k = len; k < plen; ++k) sorted[excl + k] = N_NODES;
  __syncthreads();

  int total = sc[511];
  for (int p = t; p < total; p += 512) colx[gb + p] = sorted[p];
}

// ---------- aggregation: one wave per node, dwordx4 gather = 4 rows/instr ----------
// lane (g=lane>>4, o=lane&15): loads bytes [o*16, o*16+16) of row colx[j+g].
// 8 rows in flight from 2 instrs; cross-group shfl_xor reduce at the end.
__global__ __launch_bounds__(256) void k_agg(const ushort16* __restrict__ xb, ushort16* __restrict__ ob,
                                             const int* __restrict__ rowptr, const int* __restrict__ rowlen,
                                             const int* __restrict__ colx){
  int node = (blockIdx.x*256 + threadIdx.x) >> 6;   // 25000 blocks * 4 waves
  int lane = threadIdx.x & 63;
  int g = lane >> 4, o = lane & 15;
  int j   = rowptr[node];
  int end = j + rowlen[node];
  const uint32* xw = (const uint32*)xb;

  float f0=0.f,f1=0.f,f2=0.f,f3=0.f,f4=0.f,f5=0.f,f6=0.f,f7=0.f;

  while (j + 8 <= end){
    int4 c0 = *(const int4*)(colx + j);
    int4 c1 = *(const int4*)(colx + j + 4);
    int r0ab = (g & 1) ? c0.y : c0.x;
    int r0cd = (g & 1) ? c0.w : c0.z;
    int r0   = (g & 2) ? r0cd : r0ab;
    int r1ab = (g & 1) ? c1.y : c1.x;
    int r1cd = (g & 1) ? c1.w : c1.z;
    int r1   = (g & 2) ? r1cd : r1ab;
    uint4 u0 = *(const uint4*)(xw + (size_t)r0*64 + o*4);
    uint4 u1 = *(const uint4*)(xw + (size_t)r1*64 + o*4);
    f0 += bfLo(u0.x); f1 += bfHi(u0.x); f2 += bfLo(u0.y); f3 += bfHi(u0.y);
    f4 += bfLo(u0.z); f5 += bfHi(u0.z); f6 += bfLo(u0.w); f7 += bfHi(u0.w);
    f0 += bfLo(u1.x); f1 += bfHi(u1.x); f2 += bfLo(u1.y); f3 += bfHi(u1.y);
    f4 += bfLo(u1.z); f5 += bfHi(u1.z); f6 += bfLo(u1.w); f7 += bfHi(u1.w);
    j += 8;
  }
  if (j < end){
    int4 c0 = *(const int4*)(colx + j);
    int rab = (g & 1) ? c0.y : c0.x;
    int rcd = (g & 1) ? c0.w : c0.z;
    int r0  = (g & 2) ? rcd : rab;
    uint4 u0 = *(const uint4*)(xw + (size_t)r0*64 + o*4);
    f0 += bfLo(u0.x); f1 += bfHi(u0.x); f2 += bfLo(u0.y); f3 += bfHi(u0.y);
    f4 += bfLo(u0.z); f5 += bfHi(u0.z); f6 += bfLo(u0.w); f7 += bfHi(u0.w);
  }

  // reduce over edge-slot groups (lane bits 4,5)
  f0 += __shfl_xor(f0, 16, 64); f1 += __shfl_xor(f1, 16, 64);
  f2 += __shfl_xor(f2, 16, 64); f3 += __shfl_xor(f3, 16, 64);
  f4 += __shfl_xor(f4, 16, 64); f5 += __shfl_xor(f5, 16, 64);
  f6 += __shfl_xor(f6, 16, 64); f7 += __shfl_xor(f7, 16, 64);
  f0 += __shfl_xor(f0, 32, 64); f1 += __shfl_xor(f1, 32, 64);
  f2 += __shfl_xor(f2, 32, 64); f3 += __shfl_xor(f3, 32, 64);
  f4 += __shfl_xor(f4, 32, 64); f5 += __shfl_xor(f5, 32, 64);
  f6 += __shfl_xor(f6, 32, 64); f7 += __shfl_xor(f7, 32, 64);

  if (g == 0){
    uint4 r;
    r.x = pack2(f0, f1); r.y = pack2(f2, f3);
    r.z = pack2(f4, f5); r.w = pack2(f6, f7);
    *(uint4*)(ob + (size_t)node*128 + o*8) = r;
  }
}

// ---------- fused GIN MLP: out = relu((x+agg)@W1 + b1)@W2 + b2, in-place over agg buffer ----------
__global__ __launch_bounds__(256) void k_mlp(const ushort16* __restrict__ xb, ushort16* __restrict__ hb,
                                             const ushort16* __restrict__ Wt1, const float* __restrict__ b1,
                                             const ushort16* __restrict__ Wt2, const float* __restrict__ b2){
  __shared__ __attribute__((aligned(16))) ushort16 sA[64 * LDA];
  __shared__ __attribute__((aligned(16))) ushort16 sW[128 * LDA];
  int t = threadIdx.x;
  int row0 = blockIdx.x * 64;

  int sr = t >> 4;            // 0..15
  int sc = (t & 15) * 8;      // 0,8,...,120

  #pragma unroll
  for (int it = 0; it < 4; ++it){
    int row = it*16 + sr;
    int g = row0 + row;
    uint4 o;
    if (g < N_NODES){
      uint4 xv = *(const uint4*)(xb + g*128 + sc);
      uint4 av = *(const uint4*)(hb + g*128 + sc);
      o.x = addpack(xv.x, av.x); o.y = addpack(xv.y, av.y);
      o.z = addpack(xv.z, av.z); o.w = addpack(xv.w, av.w);
    } else { o.x = o.y = o.z = o.w = 0u; }
    *(uint4*)(sA + row*LDA + sc) = o;
  }
  #pragma unroll
  for (int it = 0; it < 8; ++it){
    int row = it*16 + sr;
    *(uint4*)(sW + row*LDA + sc) = *(const uint4*)(Wt1 + row*128 + sc);
  }
  __syncthreads();

  int wave = t >> 6, l = t & 63, m = l & 15, kg = l >> 4;
  fx4 acc[8];
  #pragma unroll
  for (int nt = 0; nt < 8; ++nt) acc[nt] = (fx4){0.f,0.f,0.f,0.f};

  const ushort16* aBase = sA + (wave*16 + m)*LDA + kg*8;
  const ushort16* bBase = sW + m*LDA + kg*8;

  #pragma unroll
  for (int kt = 0; kt < 4; ++kt){
    bf16x8 av = *(const bf16x8*)(aBase + kt*32);
    #pragma unroll
    for (int nt = 0; nt < 8; ++nt){
      bf16x8 bv = *(const bf16x8*)(bBase + nt*16*LDA + kt*32);
      acc[nt] = __builtin_amdgcn_mfma_f32_16x16x32_bf16(av, bv, acc[nt], 0, 0, 0);
    }
  }
  __syncthreads();

  #pragma unroll
  for (int nt = 0; nt < 8; ++nt){
    float bv = b1[nt*16 + m];
    #pragma unroll
    for (int r = 0; r < 4; ++r){
      float v = acc[nt][r] + bv;
      v = fmaxf(v, 0.f);
      sA[(wave*16 + kg*4 + r)*LDA + nt*16 + m] = f2bf(v);
    }
  }
  #pragma unroll
  for (int it = 0; it < 8; ++it){
    int row = it*16 + sr;
    *(uint4*)(sW + row*LDA + sc) = *(const uint4*)(Wt2 + row*128 + sc);
  }
  __syncthreads();

  #pragma unroll
  for (int nt = 0; nt < 8; ++nt) acc[nt] = (fx4){0.f,0.f,0.f,0.f};

  #pragma unroll
  for (int kt = 0; kt < 4; ++kt){
    bf16x8 av = *(const bf16x8*)(aBase + kt*32);
    #pragma unroll
    for (int nt = 0; nt < 8; ++nt){
      bf16x8 bv = *(const bf16x8*)(bBase + nt*16*LDA + kt*32);
      acc[nt] = __builtin_amdgcn_mfma_f32_16x16x32_bf16(av, bv, acc[nt], 0, 0, 0);
    }
  }

  #pragma unroll
  for (int nt = 0; nt < 8; ++nt){
    float bv = b2[nt*16 + m];
    #pragma unroll
    for (int r = 0; r < 4; ++r){
      int g = row0 + wave*16 + kg*4 + r;
      if (g < N_NODES){
        float v = acc[nt][r] + bv;
        hb[g*128 + nt*16 + m] = f2bf(v);
      }
    }
  }
}

// ---------- sum-pool per graph (batch sorted) ----------
__device__ __forceinline__ int lower_bound_i(const int* __restrict__ a, int n, int key){
  int lo = 0, hi = n;
  while (lo < hi){ int mid = (lo + hi) >> 1; if (a[mid] < key) lo = mid + 1; else hi = mid; }
  return lo;
}

__global__ __launch_bounds__(256) void k_pool(const ushort16* __restrict__ xb, const int* __restrict__ batch,
                                              float* __restrict__ out){
  int g = blockIdx.x >> 2;
  int p = blockIdx.x & 3;
  int start = lower_bound_i(batch, N_NODES, g);
  int end   = lower_bound_i(batch, N_NODES, g + 1);
  int t = threadIdx.x;
  int c = t & 127;
  int h = t >> 7;
  float acc = 0.f;
  for (int r = start + p*2 + h; r < end; r += 8){
    uint32 u = (uint32)xb[r*128 + c];
    acc += __builtin_bit_cast(float, (uint32)(u << 16));
  }
  __shared__ float red[256];
  red[t] = acc; __syncthreads();
  if (t < 128) atomicAdd(&out[g*128 + c], red[t] + red[t + 128]);
}

// ---------- launch ----------
extern "C" void kernel_launch(void* const* d_in, const int* in_sizes, int n_in,
                              void* d_out, int out_size, void* d_ws, size_t ws_size,
                              hipStream_t stream) {
  const float* x   = (const float*)d_in[0];
  const float* W1  = (const float*)d_in[1];
  const float* b1  = (const float*)d_in[2];
  const float* W2  = (const float*)d_in[3];
  const float* b2  = (const float*)d_in[4];
  const int*   ei  = (const int*)d_in[5];
  const int*   bat = (const int*)d_in[6];
  float* out = (float*)d_out;

  char* w = (char*)d_ws;
  auto carve = [&](size_t bytes) -> char* {
    char* p = w; w += (bytes + 255) & ~(size_t)255; return p;
  };
  ushort16* P    = (ushort16*)carve((size_t)(N_NODES+1) * DIM * 2);  // +1: zero pad row
  ushort16* Q    = (ushort16*)carve((size_t)(N_NODES+1) * DIM * 2);
  ushort16* WtA  = (ushort16*)carve(3 * 16384 * 2);
  ushort16* WtB  = (ushort16*)carve(3 * 16384 * 2);
  int* rowptr    = (int*)carve((size_t)N_NODES * 4);
  int* rowlen    = (int*)carve((size_t)N_NODES * 4);
  int* colx      = (int*)carve((size_t)NBKT * BP * 4);   // 8.03 MB, fixed bucket regions
  int* bucketCursor = (int*)carve((NBKT + 1) * 4);
  // temp bucket regions alias Q: only live during CSR build (first 9.63 MB; zero row at 25.6 MB is safe)
  int* temp      = (int*)Q;

  hipMemsetAsync(bucketCursor, 0, (NBKT + 1) * 4, stream);
  hipMemsetAsync(d_out, 0, (size_t)N_GRAPHS * DIM * 4, stream);

  k_cvt_x<<<6251, 256, 0, stream>>>(x, P, Q);
  k_cvt_w<<<384, 256, 0, stream>>>(W1, W2, WtA, WtB);

  k_binA<<<(N_EDGES + 8191)/8192, 512, 0, stream>>>(ei, bucketCursor, temp);
  k_binB<<<NBKT, 512, 0, stream>>>(temp, bucketCursor, rowptr, rowlen, colx);

  const int aggGrid = N_NODES / 4;          // 4 waves/block, 1 node/wave
  const int mlpGrid = (N_NODES + 63) / 64;  // 1563

  // layer 0: x=P, agg->Q, mlp(P,Q)->Q
  k_agg<<<aggGrid, 256, 0, stream>>>(P, Q, rowptr, rowlen, colx);
  k_mlp<<<mlpGrid, 256, 0, stream>>>(P, Q, WtA + 0*16384, b1 + 0*128, WtB + 0*16384, b2 + 0*128);
  // layer 1: x=Q, agg->P, mlp(Q,P)->P
  k_agg<<<aggGrid, 256, 0, stream>>>(Q, P, rowptr, rowlen, colx);
  k_mlp<<<mlpGrid, 256, 0, stream>>>(Q, P, WtA + 1*16384, b1 + 1*128, WtB + 1*16384, b2 + 1*128);
  // layer 2: x=P, agg->Q, mlp(P,Q)->Q
  k_agg<<<aggGrid, 256, 0, stream>>>(P, Q, rowptr, rowlen, colx);
  k_mlp<<<mlpGrid, 256, 0, stream>>>(P, Q, WtA + 2*16384, b1 + 2*128, WtB + 2*16384, b2 + 2*128);

  k_pool<<<N_GRAPHS * 4, 256, 0, stream>>>(Q, bat, out);
}